// Round 12
// baseline (49.947 us; speedup 1.0000x reference)
//
#include <hip/hip_runtime.h>
#include <hip/hip_bf16.h>
#include <math.h>

#define B_DIM 64
#define D_DIM 256
#define C_DIM 100000
#define P_DIM 8
#define N_DIM 32
#define BLK_COLS 64
#define GBLK 1563       // ceil(C_DIM / 64)
#define NCHUNK 8        // K chunks of 32
#define NBANK 64        // exp-sum accumulator banks

typedef __attribute__((ext_vector_type(8))) short bf16x8;
typedef __attribute__((ext_vector_type(16))) float f32x16;

__device__ __forceinline__ unsigned short bf16_rn(float f) {
    unsigned int u = __float_as_uint(f);
    unsigned int r = (u + 0x7FFFu + ((u >> 16) & 1u)) >> 16;
    return (unsigned short)r;
}

// Truncate-split: x = hi + lo (hi exact truncation, lo rounds; combined ~2^-17 rel err)
__device__ __forceinline__ void split_bf16(float x, unsigned short& hi, unsigned short& lo) {
    unsigned int bx = __float_as_uint(x);
    unsigned int hb = bx & 0xFFFF0000u;
    hi = (unsigned short)(hb >> 16);
    lo = bf16_rn(x - __uint_as_float(hb));
}

__device__ __forceinline__ float softplusf(float x) { return log1pf(expf(x)); }

__device__ __forceinline__ short f2bf(float x) {
    __hip_bfloat16 b = __float2bfloat16(x);   // pairs into v_cvt_pk_bf16_f32
    return *reinterpret_cast<short*>(&b);
}

// async 16B global->LDS copy; lds base is wave-uniform (HW adds lane*16)
__device__ __forceinline__ void async_copy16(const float* src, float* lds_base) {
    __builtin_amdgcn_global_load_lds(
        (const __attribute__((address_space(1))) unsigned int*)src,
        (__attribute__((address_space(3))) unsigned int*)lds_base,
        16, 0, 0);
}

// ---------------- Kernel A: norms, sim = ni@ni^T (hi+lo MFMA), hp/hn losses, A-frag precompute ----------------
// 1024 threads: conversion/zeroing use all 16 waves; sim-MFMA on waves 0-3.
__global__ __launch_bounds__(1024)
void prep_kernel(const float* __restrict__ X,
                 const int* __restrict__ pos_idx, const int* __restrict__ pos_mask,
                 const int* __restrict__ neg_idx, const int* __restrict__ neg_mask,
                 float* __restrict__ wsH, unsigned short* __restrict__ wsA,
                 float* __restrict__ wsQ, float* __restrict__ wsT) {
    __shared__ unsigned short fHi[2048 * 8];   // 32 KB
    __shared__ unsigned short fLo[2048 * 8];   // 32 KB
    __shared__ float sim[64][64];              // 16 KB
    __shared__ float inv[64];
    __shared__ float hp[64];
    __shared__ float contrib[64];
    const int tid = threadIdx.x;
    for (int i = tid; i < NBANK * 64; i += 1024) wsQ[i] = 0.0f;
    if (tid < 64) wsT[tid] = 0.0f;
    // row norms: 4 threads per row (first 4 waves)
    if (tid < 256) {
        int r = tid >> 2, q = tid & 3;
        const float* row = X + r * D_DIM + q * 64;
        float s = 0.0f;
        #pragma unroll
        for (int i = 0; i < 64; i += 4) {
            float4 v = *(const float4*)(row + i);
            s += v.x * v.x + v.y * v.y + v.z * v.z + v.w * v.w;
        }
        s += __shfl_xor(s, 1);
        s += __shfl_xor(s, 2);
        if (q == 0) inv[r] = 1.0f / fmaxf(sqrtf(s), 1e-12f);
    }
    __syncthreads();
    // fragments: lane l holds M[mt*32+(l&31)][kg*16+8*(l>>5)+j]
    for (int t = tid; t < 2048; t += 1024) {
        int l = t & 63, kg = (t >> 6) & 15, mt = t >> 10;
        int row = mt * 32 + (l & 31);
        int col0 = kg * 16 + 8 * (l >> 5);
        const float* src = X + row * D_DIM + col0;
        float iv = inv[row];
        #pragma unroll
        for (int j = 0; j < 8; ++j) {
            unsigned short h, lo;
            split_bf16(src[j] * iv, h, lo);
            fHi[t * 8 + j] = h;
            fLo[t * 8 + j] = lo;
            wsA[t * 8 + j] = (unsigned short)f2bf(src[j]);
        }
    }
    __syncthreads();
    // sim via 4 wave tiles of 32x32 (waves 0-3)
    if ((tid >> 6) < 4) {
        int w = tid >> 6, l = tid & 63;
        int mt = w >> 1, nt = w & 1;
        f32x16 acc;
        #pragma unroll
        for (int i = 0; i < 16; ++i) acc[i] = 0.0f;
        #pragma unroll
        for (int ks = 0; ks < 16; ++ks) {
            const bf16x8 ah = *(const bf16x8*)&fHi[((mt * 16 + ks) * 64 + l) * 8];
            const bf16x8 al = *(const bf16x8*)&fLo[((mt * 16 + ks) * 64 + l) * 8];
            const bf16x8 bh = *(const bf16x8*)&fHi[((nt * 16 + ks) * 64 + l) * 8];
            const bf16x8 bl = *(const bf16x8*)&fLo[((nt * 16 + ks) * 64 + l) * 8];
            acc = __builtin_amdgcn_mfma_f32_32x32x16_bf16(ah, bh, acc, 0, 0, 0);
            acc = __builtin_amdgcn_mfma_f32_32x32x16_bf16(al, bh, acc, 0, 0, 0);
            acc = __builtin_amdgcn_mfma_f32_32x32x16_bf16(ah, bl, acc, 0, 0, 0);
        }
        #pragma unroll
        for (int r = 0; r < 16; ++r) {
            int brow = mt * 32 + (r & 3) + 8 * (r >> 2) + 4 * (l >> 5);
            int bcol = nt * 32 + (l & 31);
            sim[brow][bcol] = acc[r];
        }
    }
    __syncthreads();
    // hardest positive
    if (tid < 256) {
        int r = tid >> 2, q = tid & 3;
        const float INF = __int_as_float(0x7f800000);
        float m = INF;
        #pragma unroll
        for (int pp = 0; pp < 2; ++pp) {
            int p = q * 2 + pp;
            int j = pos_idx[r * P_DIM + p];
            int msk = pos_mask[r * P_DIM + p];
            float ps = sim[r][j];
            m = fminf(m, msk ? ps : INF);
        }
        m = fminf(m, __shfl_xor(m, 1));
        m = fminf(m, __shfl_xor(m, 2));
        if (q == 0) hp[r] = m;
    }
    __syncthreads();
    // hard negatives
    if (tid < 256) {
        int r = tid >> 2, q = tid & 3;
        float thr = hp[r] - 0.3f;
        float sum = 0.0f; int cnt = 0;
        #pragma unroll
        for (int nn = 0; nn < 8; ++nn) {
            int n = q * 8 + nn;
            int j = neg_idx[r * N_DIM + n];
            int msk = neg_mask[r * N_DIM + n];
            float ns = sim[r][j];
            if (msk && (ns > thr)) { cnt += 1; sum += softplusf(ns); }
        }
        sum += __shfl_xor(sum, 1); cnt += __shfl_xor(cnt, 1);
        sum += __shfl_xor(sum, 2); cnt += __shfl_xor(cnt, 2);
        if (q == 0) {
            float hn = (cnt > 0) ? (sum / (float)cnt) : 0.0f;
            contrib[r] = softplusf(-hp[r]) + hn;
        }
    }
    __syncthreads();
    if (tid == 0) {
        float s = 0.0f;
        for (int i = 0; i < 64; ++i) s += contrib[i];
        wsH[0] = s * (1.0f / 64.0f);
    }
}

// ---------------- Kernel B: logits^T = V_tile @ X^T, 64-col tiles, 2-wave blocks ----------------
// R11 loop (best-known). NEW: non-temporal stores for `out` — the 25.6 MB logits
// stream bypasses L3 so V stays L3-resident across graph replays (FETCH_SIZE drop).
__global__ __launch_bounds__(128)
void logits_kernel(const float* __restrict__ V, const unsigned short* __restrict__ wsA,
                   const int* __restrict__ targets, float* __restrict__ out,
                   float* __restrict__ wsQ, float* __restrict__ wsT) {
    __shared__ float shm[4352];                // stage 2x8 KB; epilogue 17 KB overlay
    __shared__ int tgt[64];
    const int tid = threadIdx.x;
    const int w = tid >> 6, l = tid & 63;      // w in {0,1}
    const int c0 = blockIdx.x * BLK_COLS;
    const int hi = l >> 5;
    if (tid < 64) tgt[tid] = targets[tid];

    // stage chunk kc (64 cols x 32 k = 8 KB) into buffer b; 16B units XOR-swizzled
    // (unit ^= col&7) applied on the GLOBAL source; gload_lds dest stays linear.
    #define STAGE(kc, b)                                                        \
        {                                                                       \
            _Pragma("unroll")                                                   \
            for (int j = 0; j < 4; ++j) {                                       \
                int U = (j * 2 + w) * 64 + l;                                   \
                int colL = U >> 3, up = U & 7;                                  \
                int us = up ^ (colL & 7);                                       \
                int cc = c0 + colL; cc = (cc < C_DIM) ? cc : (C_DIM - 1);       \
                const float* src = V + (size_t)cc * D_DIM + (kc) * 32 + us * 4; \
                async_copy16(src, &shm[(b) * 2048 + (j * 2 + w) * 256]);        \
            }                                                                   \
        }

    STAGE(0, 0);
    __syncthreads();

    f32x16 acc0, acc1;                         // batch rows 0-31, 32-63
    #pragma unroll
    for (int i = 0; i < 16; ++i) { acc0[i] = 0.0f; acc1[i] = 0.0f; }

    const int colL = w * 32 + (l & 31);
    const int cbase = colL * 32;               // 8 units * 4 floats per col
    const int cm7 = colL & 7;

    for (int kc = 0; kc < NCHUNK; ++kc) {
        if (kc < NCHUNK - 1) STAGE(kc + 1, (kc + 1) & 1);
        const float* vb = &shm[(kc & 1) * 2048];
        #pragma unroll
        for (int h = 0; h < 2; ++h) {
            const int kg = kc * 2 + h;
            const bf16x8 a0 = *(const bf16x8*)(wsA + ((0 * 16 + kg) * 64 + l) * 8);
            const bf16x8 a1 = *(const bf16x8*)(wsA + ((1 * 16 + kg) * 64 + l) * 8);
            const int u0 = h * 4 + 2 * hi;
            float4 v0 = *(const float4*)&vb[cbase + ((u0    ) ^ cm7) * 4];
            float4 v1 = *(const float4*)&vb[cbase + ((u0 + 1) ^ cm7) * 4];
            bf16x8 vh;
            vh[0] = f2bf(v0.x); vh[1] = f2bf(v0.y); vh[2] = f2bf(v0.z); vh[3] = f2bf(v0.w);
            vh[4] = f2bf(v1.x); vh[5] = f2bf(v1.y); vh[6] = f2bf(v1.z); vh[7] = f2bf(v1.w);
            // TRANSPOSED: A = V fragment, B = X fragment
            acc0 = __builtin_amdgcn_mfma_f32_32x32x16_bf16(vh, a0, acc0, 0, 0, 0);
            acc1 = __builtin_amdgcn_mfma_f32_32x32x16_bf16(vh, a1, acc1, 0, 0, 0);
        }
        __syncthreads();
    }
    #undef STAGE

    // ---- epilogue: lane-local exp-sums + target capture + LDS transpose ----
    float* ldsT = &shm[w * 2112];              // [64 b][33 c] per wave (2 waves)
    float* sred = &shm[4224];                  // [2 waves][64 b]
    const int b0 = l & 31, b1 = 32 + (l & 31);
    const int tb0 = tgt[b0], tb1 = tgt[b1];
    float s0 = 0.0f, s1 = 0.0f;
    #pragma unroll
    for (int r = 0; r < 16; ++r) {
        const int cl = (r & 3) + 8 * (r >> 2) + 4 * hi;
        const int c = c0 + w * 32 + cl;
        const float v0 = acc0[r], v1 = acc1[r];
        ldsT[b0 * 33 + cl] = v0;
        ldsT[b1 * 33 + cl] = v1;
        if (c < C_DIM) {
            s0 += expf(v0);
            s1 += expf(v1);
            if (c == tb0) atomicAdd(&wsT[b0], v0);
            if (c == tb1) atomicAdd(&wsT[b1], v1);
        }
    }
    s0 += __shfl_xor(s0, 32);                  // add the partner c-half
    s1 += __shfl_xor(s1, 32);
    if (l < 32) { sred[w * 64 + l] = s0; sred[w * 64 + 32 + l] = s1; }
    __syncthreads();
    if (tid < 64) {
        float s = sred[tid] + sred[64 + tid];
        atomicAdd(&wsQ[(blockIdx.x & (NBANK - 1)) * 64 + tid], s);
    }
    // non-temporal stores: don't let the logits stream evict V from L3
    const int cg = c0 + w * 32 + (l & 31);
    if (cg < C_DIM) {
        #pragma unroll
        for (int rr = 0; rr < 32; ++rr) {
            const int b = 2 * rr + hi;
            __builtin_nontemporal_store(ldsT[b * 33 + (l & 31)],
                                        &out[1 + (size_t)b * C_DIM + cg]);
        }
    }
}

// ---------------- Kernel C: finalize loss ----------------
__global__ __launch_bounds__(64)
void final_kernel(float* __restrict__ out, const float* __restrict__ wsQ,
                  const float* __restrict__ wsT, const float* __restrict__ wsH) {
    int b = threadIdx.x;
    float S = 0.0f;
    #pragma unroll
    for (int k = 0; k < NBANK; ++k) S += wsQ[k * 64 + b];
    float lb = logf(S) - wsT[b];
    #pragma unroll
    for (int m = 1; m <= 32; m <<= 1) lb += __shfl_xor(lb, m);
    if (b == 0) out[0] = lb * (1.0f / 64.0f) + wsH[0];
}

extern "C" void kernel_launch(void* const* d_in, const int* in_sizes, int n_in,
                              void* d_out, int out_size, void* d_ws, size_t ws_size,
                              hipStream_t stream) {
    (void)in_sizes; (void)n_in; (void)out_size; (void)ws_size;
    const float* X        = (const float*)d_in[0];
    const float* V        = (const float*)d_in[1];
    const int*   targets  = (const int*)d_in[2];
    const int*   pos_idx  = (const int*)d_in[3];
    const int*   pos_mask = (const int*)d_in[4];
    const int*   neg_idx  = (const int*)d_in[5];
    const int*   neg_mask = (const int*)d_in[6];
    float* out = (float*)d_out;
    float*          wsH = (float*)d_ws;                              // 64 floats
    float*          wsQ = (float*)d_ws + 64;                         // NBANK*64 = 4096
    float*          wsT = (float*)d_ws + 64 + NBANK * 64;            // 64
    unsigned short* wsA = (unsigned short*)((char*)d_ws + 32768);    // 32 KB A-fragments

    hipLaunchKernelGGL(prep_kernel, dim3(1), dim3(1024), 0, stream,
                       X, pos_idx, pos_mask, neg_idx, neg_mask, wsH, wsA, wsQ, wsT);
    hipLaunchKernelGGL(logits_kernel, dim3(GBLK), dim3(128), 0, stream,
                       V, wsA, targets, out, wsQ, wsT);
    hipLaunchKernelGGL(final_kernel, dim3(1), dim3(64), 0, stream, out, wsQ, wsT, wsH);
}

// Round 13
// 46.031 us; speedup vs baseline: 1.0851x; 1.0851x over previous
//
#include <hip/hip_runtime.h>
#include <hip/hip_bf16.h>
#include <math.h>

#define B_DIM 64
#define D_DIM 256
#define C_DIM 100000
#define P_DIM 8
#define N_DIM 32
#define BLK_COLS 64
#define GBLK 1563       // ceil(C_DIM / 64)
#define NCHUNK 8        // K chunks of 32
#define NBANK 64        // exp-sum accumulator banks

typedef __attribute__((ext_vector_type(8))) short bf16x8;
typedef __attribute__((ext_vector_type(16))) float f32x16;

__device__ __forceinline__ unsigned short bf16_rn(float f) {
    unsigned int u = __float_as_uint(f);
    unsigned int r = (u + 0x7FFFu + ((u >> 16) & 1u)) >> 16;
    return (unsigned short)r;
}

// Truncate-split: x = hi + lo (hi exact truncation, lo rounds; combined ~2^-17 rel err)
__device__ __forceinline__ void split_bf16(float x, unsigned short& hi, unsigned short& lo) {
    unsigned int bx = __float_as_uint(x);
    unsigned int hb = bx & 0xFFFF0000u;
    hi = (unsigned short)(hb >> 16);
    lo = bf16_rn(x - __uint_as_float(hb));
}

__device__ __forceinline__ float softplusf(float x) { return log1pf(expf(x)); }

__device__ __forceinline__ short f2bf(float x) {
    __hip_bfloat16 b = __float2bfloat16(x);   // pairs into v_cvt_pk_bf16_f32
    return *reinterpret_cast<short*>(&b);
}

// async 16B global->LDS copy; lds base is wave-uniform (HW adds lane*16)
__device__ __forceinline__ void async_copy16(const float* src, float* lds_base) {
    __builtin_amdgcn_global_load_lds(
        (const __attribute__((address_space(1))) unsigned int*)src,
        (__attribute__((address_space(3))) unsigned int*)lds_base,
        16, 0, 0);
}

// ---------------- Kernel A: norms, sim = ni@ni^T (hi+lo MFMA), hp/hn losses, A-frag precompute ----------------
__global__ __launch_bounds__(512)
void prep_kernel(const float* __restrict__ X,
                 const int* __restrict__ pos_idx, const int* __restrict__ pos_mask,
                 const int* __restrict__ neg_idx, const int* __restrict__ neg_mask,
                 float* __restrict__ wsH, unsigned short* __restrict__ wsA,
                 float* __restrict__ wsQ, float* __restrict__ wsT) {
    __shared__ unsigned short fHi[2048 * 8];   // 32 KB
    __shared__ unsigned short fLo[2048 * 8];   // 32 KB
    __shared__ float sim[64][64];              // 16 KB
    __shared__ float inv[64];
    __shared__ float hp[64];
    __shared__ float contrib[64];
    const int tid = threadIdx.x;
    for (int i = tid; i < NBANK * 64; i += 512) wsQ[i] = 0.0f;
    if (tid < 64) wsT[tid] = 0.0f;
    // row norms: 4 threads per row (first 4 waves)
    if (tid < 256) {
        int r = tid >> 2, q = tid & 3;
        const float* row = X + r * D_DIM + q * 64;
        float s = 0.0f;
        #pragma unroll
        for (int i = 0; i < 64; i += 4) {
            float4 v = *(const float4*)(row + i);
            s += v.x * v.x + v.y * v.y + v.z * v.z + v.w * v.w;
        }
        s += __shfl_xor(s, 1);
        s += __shfl_xor(s, 2);
        if (q == 0) inv[r] = 1.0f / fmaxf(sqrtf(s), 1e-12f);
    }
    __syncthreads();
    // fragments: lane l holds M[mt*32+(l&31)][kg*16+8*(l>>5)+j]
    for (int t = tid; t < 2048; t += 512) {
        int l = t & 63, kg = (t >> 6) & 15, mt = t >> 10;
        int row = mt * 32 + (l & 31);
        int col0 = kg * 16 + 8 * (l >> 5);
        const float* src = X + row * D_DIM + col0;
        float iv = inv[row];
        #pragma unroll
        for (int j = 0; j < 8; ++j) {
            unsigned short h, lo;
            split_bf16(src[j] * iv, h, lo);
            fHi[t * 8 + j] = h;
            fLo[t * 8 + j] = lo;
            wsA[t * 8 + j] = (unsigned short)f2bf(src[j]);
        }
    }
    __syncthreads();
    // sim via 4 wave tiles of 32x32 (waves 0-3)
    if ((tid >> 6) < 4) {
        int w = tid >> 6, l = tid & 63;
        int mt = w >> 1, nt = w & 1;
        f32x16 acc;
        #pragma unroll
        for (int i = 0; i < 16; ++i) acc[i] = 0.0f;
        #pragma unroll
        for (int ks = 0; ks < 16; ++ks) {
            const bf16x8 ah = *(const bf16x8*)&fHi[((mt * 16 + ks) * 64 + l) * 8];
            const bf16x8 al = *(const bf16x8*)&fLo[((mt * 16 + ks) * 64 + l) * 8];
            const bf16x8 bh = *(const bf16x8*)&fHi[((nt * 16 + ks) * 64 + l) * 8];
            const bf16x8 bl = *(const bf16x8*)&fLo[((nt * 16 + ks) * 64 + l) * 8];
            acc = __builtin_amdgcn_mfma_f32_32x32x16_bf16(ah, bh, acc, 0, 0, 0);
            acc = __builtin_amdgcn_mfma_f32_32x32x16_bf16(al, bh, acc, 0, 0, 0);
            acc = __builtin_amdgcn_mfma_f32_32x32x16_bf16(ah, bl, acc, 0, 0, 0);
        }
        #pragma unroll
        for (int r = 0; r < 16; ++r) {
            int brow = mt * 32 + (r & 3) + 8 * (r >> 2) + 4 * (l >> 5);
            int bcol = nt * 32 + (l & 31);
            sim[brow][bcol] = acc[r];
        }
    }
    __syncthreads();
    // hardest positive
    if (tid < 256) {
        int r = tid >> 2, q = tid & 3;
        const float INF = __int_as_float(0x7f800000);
        float m = INF;
        #pragma unroll
        for (int pp = 0; pp < 2; ++pp) {
            int p = q * 2 + pp;
            int j = pos_idx[r * P_DIM + p];
            int msk = pos_mask[r * P_DIM + p];
            float ps = sim[r][j];
            m = fminf(m, msk ? ps : INF);
        }
        m = fminf(m, __shfl_xor(m, 1));
        m = fminf(m, __shfl_xor(m, 2));
        if (q == 0) hp[r] = m;
    }
    __syncthreads();
    // hard negatives
    if (tid < 256) {
        int r = tid >> 2, q = tid & 3;
        float thr = hp[r] - 0.3f;
        float sum = 0.0f; int cnt = 0;
        #pragma unroll
        for (int nn = 0; nn < 8; ++nn) {
            int n = q * 8 + nn;
            int j = neg_idx[r * N_DIM + n];
            int msk = neg_mask[r * N_DIM + n];
            float ns = sim[r][j];
            if (msk && (ns > thr)) { cnt += 1; sum += softplusf(ns); }
        }
        sum += __shfl_xor(sum, 1); cnt += __shfl_xor(cnt, 1);
        sum += __shfl_xor(sum, 2); cnt += __shfl_xor(cnt, 2);
        if (q == 0) {
            float hn = (cnt > 0) ? (sum / (float)cnt) : 0.0f;
            contrib[r] = softplusf(-hp[r]) + hn;
        }
    }
    __syncthreads();
    if (tid == 0) {
        float s = 0.0f;
        for (int i = 0; i < 64; ++i) s += contrib[i];
        wsH[0] = s * (1.0f / 64.0f);
    }
}

// ---------------- Kernel B: logits^T = V_tile @ X^T, quadrant waves, reg-hoisted A ----------------
// 256 thr / 4 waves; 64 V-cols per block; wave (wc=w&1, wr=w>>1) owns (col-half, row-half).
// ALL 16 A-fragments per wave hoisted to registers BEFORE the K-loop: the loop body's
// only VMEM is the stage, so MFMA waits are lgkmcnt-only and stage(kc+1) overlaps
// compute(kc) within the block (fixes the in-order-vmcnt serialization of R7/R11).
__global__ __launch_bounds__(256)
void logits_kernel(const float* __restrict__ V, const unsigned short* __restrict__ wsA,
                   const int* __restrict__ targets, float* __restrict__ out,
                   float* __restrict__ wsQ, float* __restrict__ wsT) {
    __shared__ float shm[4352];                // stage 2x8 KB; epilogue: ldsT[64][65]+sred
    __shared__ int tgt[64];
    const int tid = threadIdx.x;
    const int w = tid >> 6, l = tid & 63;
    const int wc = w & 1, wr = w >> 1;
    const int c0 = blockIdx.x * BLK_COLS;
    const int hi = l >> 5;
    if (tid < 64) tgt[tid] = targets[tid];

    // hoist this wave's 16 A-fragments (issued first => oldest in vmcnt queue)
    bf16x8 frg[16];
    #pragma unroll
    for (int kg = 0; kg < 16; ++kg)
        frg[kg] = *(const bf16x8*)(wsA + ((wr * 16 + kg) * 64 + l) * 8);

    // stage chunk kc (64 cols x 32 k = 8 KB); 16B units XOR-swizzled (unit ^= col&7)
    // on the GLOBAL source; gload_lds dest stays linear.
    #define STAGE(kc, b)                                                        \
        {                                                                       \
            _Pragma("unroll")                                                   \
            for (int j = 0; j < 2; ++j) {                                       \
                int U = (j * 4 + w) * 64 + l;                                   \
                int colL = U >> 3, up = U & 7;                                  \
                int us = up ^ (colL & 7);                                       \
                int cc = c0 + colL; cc = (cc < C_DIM) ? cc : (C_DIM - 1);       \
                const float* src = V + (size_t)cc * D_DIM + (kc) * 32 + us * 4; \
                async_copy16(src, &shm[(b) * 2048 + (j * 4 + w) * 256]);        \
            }                                                                   \
        }

    STAGE(0, 0);
    __syncthreads();

    f32x16 acc;
    #pragma unroll
    for (int i = 0; i < 16; ++i) acc[i] = 0.0f;

    const int colL = wc * 32 + (l & 31);
    const int cbase = colL * 32;               // 8 units * 4 floats per col
    const int cm7 = colL & 7;

    #pragma unroll
    for (int kc = 0; kc < NCHUNK; ++kc) {
        if (kc < NCHUNK - 1) STAGE(kc + 1, (kc + 1) & 1);
        const float* vb = &shm[(kc & 1) * 2048];
        #pragma unroll
        for (int h = 0; h < 2; ++h) {
            const int u0 = h * 4 + 2 * hi;
            float4 v0 = *(const float4*)&vb[cbase + ((u0    ) ^ cm7) * 4];
            float4 v1 = *(const float4*)&vb[cbase + ((u0 + 1) ^ cm7) * 4];
            bf16x8 vh;
            vh[0] = f2bf(v0.x); vh[1] = f2bf(v0.y); vh[2] = f2bf(v0.z); vh[3] = f2bf(v0.w);
            vh[4] = f2bf(v1.x); vh[5] = f2bf(v1.y); vh[6] = f2bf(v1.z); vh[7] = f2bf(v1.w);
            // TRANSPOSED: A = V fragment, B = X fragment (register)
            acc = __builtin_amdgcn_mfma_f32_32x32x16_bf16(vh, frg[kc * 2 + h], acc, 0, 0, 0);
        }
        __syncthreads();
    }
    #undef STAGE

    // ---- epilogue: lane-local exp-sums + target capture + LDS transpose ----
    float* ldsT = shm;                         // [64 rows][65]
    float* sred = &shm[4160];                  // [4 waves][32 rows]
    const int b = wr * 32 + (l & 31);          // this lane's batch row
    const int tb = tgt[b];
    float s = 0.0f;
    #pragma unroll
    for (int r = 0; r < 16; ++r) {
        const int cl = (r & 3) + 8 * (r >> 2) + 4 * hi;   // col within wave's 32
        const int c = c0 + wc * 32 + cl;
        const float v = acc[r];
        ldsT[b * 65 + wc * 32 + cl] = v;
        if (c < C_DIM) {
            s += expf(v);
            if (c == tb) atomicAdd(&wsT[b], v);
        }
    }
    s += __shfl_xor(s, 32);                    // combine the two col-subsets of this row
    if (l < 32) sred[w * 32 + l] = s;
    __syncthreads();
    if (tid < 64) {
        const int rw = (tid >> 5) * 2;         // waves covering this row: rw, rw+1
        float t = sred[rw * 32 + (tid & 31)] + sred[(rw + 1) * 32 + (tid & 31)];
        atomicAdd(&wsQ[(blockIdx.x & (NBANK - 1)) * 64 + tid], t);
    }
    // coalesced stores: lane l -> col c0+l; each thread 16 rows
    const int cg = c0 + l;
    if (cg < C_DIM) {
        #pragma unroll
        for (int rr = 0; rr < 16; ++rr) {
            const int bb = rr * 4 + w;
            out[1 + (size_t)bb * C_DIM + cg] = ldsT[bb * 65 + l];
        }
    }
}

// ---------------- Kernel C: finalize loss ----------------
__global__ __launch_bounds__(64)
void final_kernel(float* __restrict__ out, const float* __restrict__ wsQ,
                  const float* __restrict__ wsT, const float* __restrict__ wsH) {
    int b = threadIdx.x;
    float S = 0.0f;
    #pragma unroll
    for (int k = 0; k < NBANK; ++k) S += wsQ[k * 64 + b];
    float lb = logf(S) - wsT[b];
    #pragma unroll
    for (int m = 1; m <= 32; m <<= 1) lb += __shfl_xor(lb, m);
    if (b == 0) out[0] = lb * (1.0f / 64.0f) + wsH[0];
}

extern "C" void kernel_launch(void* const* d_in, const int* in_sizes, int n_in,
                              void* d_out, int out_size, void* d_ws, size_t ws_size,
                              hipStream_t stream) {
    (void)in_sizes; (void)n_in; (void)out_size; (void)ws_size;
    const float* X        = (const float*)d_in[0];
    const float* V        = (const float*)d_in[1];
    const int*   targets  = (const int*)d_in[2];
    const int*   pos_idx  = (const int*)d_in[3];
    const int*   pos_mask = (const int*)d_in[4];
    const int*   neg_idx  = (const int*)d_in[5];
    const int*   neg_mask = (const int*)d_in[6];
    float* out = (float*)d_out;
    float*          wsH = (float*)d_ws;                              // 64 floats
    float*          wsQ = (float*)d_ws + 64;                         // NBANK*64 = 4096
    float*          wsT = (float*)d_ws + 64 + NBANK * 64;            // 64
    unsigned short* wsA = (unsigned short*)((char*)d_ws + 32768);    // 32 KB A-fragments

    hipLaunchKernelGGL(prep_kernel, dim3(1), dim3(512), 0, stream,
                       X, pos_idx, pos_mask, neg_idx, neg_mask, wsH, wsA, wsQ, wsT);
    hipLaunchKernelGGL(logits_kernel, dim3(GBLK), dim3(256), 0, stream,
                       V, wsA, targets, out, wsQ, wsT);
    hipLaunchKernelGGL(final_kernel, dim3(1), dim3(64), 0, stream, out, wsQ, wsT, wsH);
}

// Round 14
// 43.518 us; speedup vs baseline: 1.1477x; 1.0577x over previous
//
#include <hip/hip_runtime.h>
#include <hip/hip_bf16.h>
#include <math.h>

#define B_DIM 64
#define D_DIM 256
#define C_DIM 100000
#define P_DIM 8
#define N_DIM 32
#define BLK_COLS 64
#define GBLK 1563       // ceil(C_DIM / 64)
#define NCHUNK 8        // K chunks of 32
#define NBANK 64        // exp-sum accumulator banks

typedef __attribute__((ext_vector_type(8))) short bf16x8;
typedef __attribute__((ext_vector_type(16))) float f32x16;

__device__ __forceinline__ unsigned short bf16_rn(float f) {
    unsigned int u = __float_as_uint(f);
    unsigned int r = (u + 0x7FFFu + ((u >> 16) & 1u)) >> 16;
    return (unsigned short)r;
}

// Truncate-split: x = hi + lo (hi exact truncation, lo rounds; combined ~2^-17 rel err)
__device__ __forceinline__ void split_bf16(float x, unsigned short& hi, unsigned short& lo) {
    unsigned int bx = __float_as_uint(x);
    unsigned int hb = bx & 0xFFFF0000u;
    hi = (unsigned short)(hb >> 16);
    lo = bf16_rn(x - __uint_as_float(hb));
}

__device__ __forceinline__ float softplusf(float x) { return log1pf(expf(x)); }

__device__ __forceinline__ short f2bf(float x) {
    __hip_bfloat16 b = __float2bfloat16(x);   // pairs into v_cvt_pk_bf16_f32
    return *reinterpret_cast<short*>(&b);
}

// async 16B global->LDS copy; lds base is wave-uniform (HW adds lane*16)
__device__ __forceinline__ void async_copy16(const float* src, float* lds_base) {
    __builtin_amdgcn_global_load_lds(
        (const __attribute__((address_space(1))) unsigned int*)src,
        (__attribute__((address_space(3))) unsigned int*)lds_base,
        16, 0, 0);
}

// ---------------- Kernel A: norms, sim = ni@ni^T (hi+lo MFMA), hp/hn losses, A-frag precompute ----------------
__global__ __launch_bounds__(512)
void prep_kernel(const float* __restrict__ X,
                 const int* __restrict__ pos_idx, const int* __restrict__ pos_mask,
                 const int* __restrict__ neg_idx, const int* __restrict__ neg_mask,
                 float* __restrict__ wsH, unsigned short* __restrict__ wsA,
                 float* __restrict__ wsQ, float* __restrict__ wsT) {
    __shared__ unsigned short fHi[2048 * 8];   // 32 KB
    __shared__ unsigned short fLo[2048 * 8];   // 32 KB
    __shared__ float sim[64][64];              // 16 KB
    __shared__ float inv[64];
    __shared__ float hp[64];
    __shared__ float contrib[64];
    const int tid = threadIdx.x;
    for (int i = tid; i < NBANK * 64; i += 512) wsQ[i] = 0.0f;
    if (tid < 64) wsT[tid] = 0.0f;
    // row norms: 4 threads per row (first 4 waves)
    if (tid < 256) {
        int r = tid >> 2, q = tid & 3;
        const float* row = X + r * D_DIM + q * 64;
        float s = 0.0f;
        #pragma unroll
        for (int i = 0; i < 64; i += 4) {
            float4 v = *(const float4*)(row + i);
            s += v.x * v.x + v.y * v.y + v.z * v.z + v.w * v.w;
        }
        s += __shfl_xor(s, 1);
        s += __shfl_xor(s, 2);
        if (q == 0) inv[r] = 1.0f / fmaxf(sqrtf(s), 1e-12f);
    }
    __syncthreads();
    // fragments: lane l holds M[mt*32+(l&31)][kg*16+8*(l>>5)+j]
    for (int t = tid; t < 2048; t += 512) {
        int l = t & 63, kg = (t >> 6) & 15, mt = t >> 10;
        int row = mt * 32 + (l & 31);
        int col0 = kg * 16 + 8 * (l >> 5);
        const float* src = X + row * D_DIM + col0;
        float iv = inv[row];
        #pragma unroll
        for (int j = 0; j < 8; ++j) {
            unsigned short h, lo;
            split_bf16(src[j] * iv, h, lo);
            fHi[t * 8 + j] = h;
            fLo[t * 8 + j] = lo;
            wsA[t * 8 + j] = (unsigned short)f2bf(src[j]);
        }
    }
    __syncthreads();
    // sim via 4 wave tiles of 32x32 (waves 0-3)
    if ((tid >> 6) < 4) {
        int w = tid >> 6, l = tid & 63;
        int mt = w >> 1, nt = w & 1;
        f32x16 acc;
        #pragma unroll
        for (int i = 0; i < 16; ++i) acc[i] = 0.0f;
        #pragma unroll
        for (int ks = 0; ks < 16; ++ks) {
            const bf16x8 ah = *(const bf16x8*)&fHi[((mt * 16 + ks) * 64 + l) * 8];
            const bf16x8 al = *(const bf16x8*)&fLo[((mt * 16 + ks) * 64 + l) * 8];
            const bf16x8 bh = *(const bf16x8*)&fHi[((nt * 16 + ks) * 64 + l) * 8];
            const bf16x8 bl = *(const bf16x8*)&fLo[((nt * 16 + ks) * 64 + l) * 8];
            acc = __builtin_amdgcn_mfma_f32_32x32x16_bf16(ah, bh, acc, 0, 0, 0);
            acc = __builtin_amdgcn_mfma_f32_32x32x16_bf16(al, bh, acc, 0, 0, 0);
            acc = __builtin_amdgcn_mfma_f32_32x32x16_bf16(ah, bl, acc, 0, 0, 0);
        }
        #pragma unroll
        for (int r = 0; r < 16; ++r) {
            int brow = mt * 32 + (r & 3) + 8 * (r >> 2) + 4 * (l >> 5);
            int bcol = nt * 32 + (l & 31);
            sim[brow][bcol] = acc[r];
        }
    }
    __syncthreads();
    // hardest positive
    if (tid < 256) {
        int r = tid >> 2, q = tid & 3;
        const float INF = __int_as_float(0x7f800000);
        float m = INF;
        #pragma unroll
        for (int pp = 0; pp < 2; ++pp) {
            int p = q * 2 + pp;
            int j = pos_idx[r * P_DIM + p];
            int msk = pos_mask[r * P_DIM + p];
            float ps = sim[r][j];
            m = fminf(m, msk ? ps : INF);
        }
        m = fminf(m, __shfl_xor(m, 1));
        m = fminf(m, __shfl_xor(m, 2));
        if (q == 0) hp[r] = m;
    }
    __syncthreads();
    // hard negatives
    if (tid < 256) {
        int r = tid >> 2, q = tid & 3;
        float thr = hp[r] - 0.3f;
        float sum = 0.0f; int cnt = 0;
        #pragma unroll
        for (int nn = 0; nn < 8; ++nn) {
            int n = q * 8 + nn;
            int j = neg_idx[r * N_DIM + n];
            int msk = neg_mask[r * N_DIM + n];
            float ns = sim[r][j];
            if (msk && (ns > thr)) { cnt += 1; sum += softplusf(ns); }
        }
        sum += __shfl_xor(sum, 1); cnt += __shfl_xor(cnt, 1);
        sum += __shfl_xor(sum, 2); cnt += __shfl_xor(cnt, 2);
        if (q == 0) {
            float hn = (cnt > 0) ? (sum / (float)cnt) : 0.0f;
            contrib[r] = softplusf(-hp[r]) + hn;
        }
    }
    __syncthreads();
    if (tid == 0) {
        float s = 0.0f;
        for (int i = 0; i < 64; ++i) s += contrib[i];
        wsH[0] = s * (1.0f / 64.0f);
    }
}

// ---------------- Kernel B: logits^T = V_tile @ X^T, 64-col tiles, 2-wave blocks ----------------
// R11 structure (best measured): chunk K=32, dbuf async-LDS, plain __syncthreads, XOR
// swizzle on global source; 64 cols / 128 thr => ~17.5 KB LDS => 8-9 blocks/CU.
__global__ __launch_bounds__(128)
void logits_kernel(const float* __restrict__ V, const unsigned short* __restrict__ wsA,
                   const int* __restrict__ targets, float* __restrict__ out,
                   float* __restrict__ wsQ, float* __restrict__ wsT) {
    __shared__ float shm[4352];                // stage 2x8 KB; epilogue 17 KB overlay
    __shared__ int tgt[64];
    const int tid = threadIdx.x;
    const int w = tid >> 6, l = tid & 63;      // w in {0,1}
    const int c0 = blockIdx.x * BLK_COLS;
    const int hi = l >> 5;
    if (tid < 64) tgt[tid] = targets[tid];

    // stage chunk kc (64 cols x 32 k = 8 KB) into buffer b; 16B units XOR-swizzled
    // (unit ^= col&7) applied on the GLOBAL source; gload_lds dest stays linear.
    #define STAGE(kc, b)                                                        \
        {                                                                       \
            _Pragma("unroll")                                                   \
            for (int j = 0; j < 4; ++j) {                                       \
                int U = (j * 2 + w) * 64 + l;                                   \
                int colL = U >> 3, up = U & 7;                                  \
                int us = up ^ (colL & 7);                                       \
                int cc = c0 + colL; cc = (cc < C_DIM) ? cc : (C_DIM - 1);       \
                const float* src = V + (size_t)cc * D_DIM + (kc) * 32 + us * 4; \
                async_copy16(src, &shm[(b) * 2048 + (j * 2 + w) * 256]);        \
            }                                                                   \
        }

    STAGE(0, 0);
    __syncthreads();

    f32x16 acc0, acc1;                         // batch rows 0-31, 32-63
    #pragma unroll
    for (int i = 0; i < 16; ++i) { acc0[i] = 0.0f; acc1[i] = 0.0f; }

    const int colL = w * 32 + (l & 31);
    const int cbase = colL * 32;               // 8 units * 4 floats per col
    const int cm7 = colL & 7;

    for (int kc = 0; kc < NCHUNK; ++kc) {
        if (kc < NCHUNK - 1) STAGE(kc + 1, (kc + 1) & 1);
        const float* vb = &shm[(kc & 1) * 2048];
        #pragma unroll
        for (int h = 0; h < 2; ++h) {
            const int kg = kc * 2 + h;
            const bf16x8 a0 = *(const bf16x8*)(wsA + ((0 * 16 + kg) * 64 + l) * 8);
            const bf16x8 a1 = *(const bf16x8*)(wsA + ((1 * 16 + kg) * 64 + l) * 8);
            const int u0 = h * 4 + 2 * hi;
            float4 v0 = *(const float4*)&vb[cbase + ((u0    ) ^ cm7) * 4];
            float4 v1 = *(const float4*)&vb[cbase + ((u0 + 1) ^ cm7) * 4];
            bf16x8 vh;
            vh[0] = f2bf(v0.x); vh[1] = f2bf(v0.y); vh[2] = f2bf(v0.z); vh[3] = f2bf(v0.w);
            vh[4] = f2bf(v1.x); vh[5] = f2bf(v1.y); vh[6] = f2bf(v1.z); vh[7] = f2bf(v1.w);
            // TRANSPOSED: A = V fragment, B = X fragment
            acc0 = __builtin_amdgcn_mfma_f32_32x32x16_bf16(vh, a0, acc0, 0, 0, 0);
            acc1 = __builtin_amdgcn_mfma_f32_32x32x16_bf16(vh, a1, acc1, 0, 0, 0);
        }
        __syncthreads();
    }
    #undef STAGE

    // ---- epilogue: lane-local exp-sums + target capture + LDS transpose ----
    float* ldsT = &shm[w * 2112];              // [64 b][33 c] per wave (2 waves)
    float* sred = &shm[4224];                  // [2 waves][64 b]
    const int b0 = l & 31, b1 = 32 + (l & 31);
    const int tb0 = tgt[b0], tb1 = tgt[b1];
    float s0 = 0.0f, s1 = 0.0f;
    #pragma unroll
    for (int r = 0; r < 16; ++r) {
        const int cl = (r & 3) + 8 * (r >> 2) + 4 * hi;
        const int c = c0 + w * 32 + cl;
        const float v0 = acc0[r], v1 = acc1[r];
        ldsT[b0 * 33 + cl] = v0;
        ldsT[b1 * 33 + cl] = v1;
        if (c < C_DIM) {
            s0 += expf(v0);
            s1 += expf(v1);
            if (c == tb0) atomicAdd(&wsT[b0], v0);
            if (c == tb1) atomicAdd(&wsT[b1], v1);
        }
    }
    s0 += __shfl_xor(s0, 32);                  // add the partner c-half
    s1 += __shfl_xor(s1, 32);
    if (l < 32) { sred[w * 64 + l] = s0; sred[w * 64 + 32 + l] = s1; }
    __syncthreads();
    if (tid < 64) {
        float s = sred[tid] + sred[64 + tid];
        atomicAdd(&wsQ[(blockIdx.x & (NBANK - 1)) * 64 + tid], s);
    }
    // store this wave's 32 columns (contiguous 128B segments per instruction)
    const int cg = c0 + w * 32 + (l & 31);
    if (cg < C_DIM) {
        #pragma unroll
        for (int rr = 0; rr < 32; ++rr) {
            const int b = 2 * rr + hi;
            out[1 + (size_t)b * C_DIM + cg] = ldsT[b * 33 + (l & 31)];
        }
    }
}

// ---------------- Kernel C: finalize loss ----------------
__global__ __launch_bounds__(64)
void final_kernel(float* __restrict__ out, const float* __restrict__ wsQ,
                  const float* __restrict__ wsT, const float* __restrict__ wsH) {
    int b = threadIdx.x;
    float S = 0.0f;
    #pragma unroll
    for (int k = 0; k < NBANK; ++k) S += wsQ[k * 64 + b];
    float lb = logf(S) - wsT[b];
    #pragma unroll
    for (int m = 1; m <= 32; m <<= 1) lb += __shfl_xor(lb, m);
    if (b == 0) out[0] = lb * (1.0f / 64.0f) + wsH[0];
}

extern "C" void kernel_launch(void* const* d_in, const int* in_sizes, int n_in,
                              void* d_out, int out_size, void* d_ws, size_t ws_size,
                              hipStream_t stream) {
    (void)in_sizes; (void)n_in; (void)out_size; (void)ws_size;
    const float* X        = (const float*)d_in[0];
    const float* V        = (const float*)d_in[1];
    const int*   targets  = (const int*)d_in[2];
    const int*   pos_idx  = (const int*)d_in[3];
    const int*   pos_mask = (const int*)d_in[4];
    const int*   neg_idx  = (const int*)d_in[5];
    const int*   neg_mask = (const int*)d_in[6];
    float* out = (float*)d_out;
    float*          wsH = (float*)d_ws;                              // 64 floats
    float*          wsQ = (float*)d_ws + 64;                         // NBANK*64 = 4096
    float*          wsT = (float*)d_ws + 64 + NBANK * 64;            // 64
    unsigned short* wsA = (unsigned short*)((char*)d_ws + 32768);    // 32 KB A-fragments

    hipLaunchKernelGGL(prep_kernel, dim3(1), dim3(512), 0, stream,
                       X, pos_idx, pos_mask, neg_idx, neg_mask, wsH, wsA, wsQ, wsT);
    hipLaunchKernelGGL(logits_kernel, dim3(GBLK), dim3(128), 0, stream,
                       V, wsA, targets, out, wsQ, wsT);
    hipLaunchKernelGGL(final_kernel, dim3(1), dim3(64), 0, stream, out, wsQ, wsT, wsH);
}